// Round 4
// baseline (490.703 us; speedup 1.0000x reference)
//
#include <hip/hip_runtime.h>
#include <math.h>

#define BB 16
#define MM 512
#define LL 1024
#define DD 128
#define KK 16
#define HH 8
#define DHH 16
#define NDFF 512
#define NNODE (BB*MM)      // 8192
#define NEDGE (NNODE*KK)   // 131072

typedef __attribute__((ext_vector_type(8))) short bf16x8;
typedef __attribute__((ext_vector_type(4))) float f32x4;
#define MFMA(a,b,c) __builtin_amdgcn_mfma_f32_16x16x32_bf16(a,b,c,0,0,0)

__device__ inline unsigned short bf16rne(float x) {
  union { float f; unsigned u; } v; v.f = x;
  return (unsigned short)((v.u + 0x7FFFu + ((v.u >> 16) & 1u)) >> 16);
}
__device__ inline float bf16tof(unsigned short h) {
  union { unsigned u; float f; } v; v.u = ((unsigned)h) << 16; return v.f;
}

// split 8 consecutive fp32 into hi/lo bf16x8, store 16B each
__device__ inline void split8_store(const float* p, short* dh, short* dl) {
  float4 x0 = *(const float4*)p;
  float4 x1 = *(const float4*)(p + 4);
  float xs[8] = {x0.x, x0.y, x0.z, x0.w, x1.x, x1.y, x1.z, x1.w};
  unsigned hu[4], lu[4];
  #pragma unroll
  for (int j = 0; j < 4; ++j) {
    unsigned short h0 = bf16rne(xs[2*j]);
    unsigned short h1 = bf16rne(xs[2*j+1]);
    unsigned short l0 = bf16rne(xs[2*j]   - bf16tof(h0));
    unsigned short l1 = bf16rne(xs[2*j+1] - bf16tof(h1));
    hu[j] = (unsigned)h0 | ((unsigned)h1 << 16);
    lu[j] = (unsigned)l0 | ((unsigned)l1 << 16);
  }
  *(uint4*)dh = make_uint4(hu[0], hu[1], hu[2], hu[3]);
  *(uint4*)dl = make_uint4(lu[0], lu[1], lu[2], lu[3]);
}

// ---------------- transpose x_enc [b][l][m] -> xt [b][m][l] ----------------
__global__ __launch_bounds__(256) void transpose_x_kernel(const float* __restrict__ X,
                                                          float* __restrict__ XT) {
  __shared__ float t[32][33];
  int b = blockIdx.z;
  int m0 = blockIdx.x * 32, l0 = blockIdx.y * 32;
  int c = threadIdx.x & 31, r = threadIdx.x >> 5;   // r 0..7
  const float* Xb = X + (size_t)b * LL * MM;
  #pragma unroll
  for (int i = 0; i < 4; ++i)
    t[r + i*8][c] = Xb[(size_t)(l0 + r + i*8) * MM + m0 + c];
  __syncthreads();
  float* XTb = XT + (size_t)b * MM * LL;
  #pragma unroll
  for (int i = 0; i < 4; ++i)
    XTb[(size_t)(m0 + r + i*8) * LL + l0 + c] = t[c][r + i*8];
}

// ---------------- transpose all weights [K][N] -> wT [N][K] ----------------
// z: 0..9 = {gw1,gw2,Wq0,Wq1,Wk0,Wk1,Wv0,Wv1,Wo0,Wo1} (128x128)
//    10,11 = W1 l (128x512) -> [512][128];  12,13 = W2 l (512x128) -> [128][512]
__global__ __launch_bounds__(256) void transpose_w_kernel(
    const float* __restrict__ gw1, const float* __restrict__ gw2,
    const float* __restrict__ Wq, const float* __restrict__ Wk,
    const float* __restrict__ Wv, const float* __restrict__ Wo,
    const float* __restrict__ W1, const float* __restrict__ W2,
    float* __restrict__ wT) {
  int z = blockIdx.z;
  const float* src; int K, N; size_t doff;
  if (z < 10) {
    K = 128; N = 128; doff = (size_t)z * 16384;
    switch (z) {
      case 0: src = gw1; break;       case 1: src = gw2; break;
      case 2: src = Wq; break;        case 3: src = Wq + 16384; break;
      case 4: src = Wk; break;        case 5: src = Wk + 16384; break;
      case 6: src = Wv; break;        case 7: src = Wv + 16384; break;
      case 8: src = Wo; break;        default: src = Wo + 16384; break;
    }
  } else if (z < 12) {
    K = 128; N = 512; doff = 163840 + (size_t)(z - 10) * 65536;
    src = W1 + (size_t)(z - 10) * 65536;
  } else {
    K = 512; N = 128; doff = 294912 + (size_t)(z - 12) * 65536;
    src = W2 + (size_t)(z - 12) * 65536;
  }
  int k0 = blockIdx.x * 32, n0 = blockIdx.y * 32;
  if (k0 >= K || n0 >= N) return;
  __shared__ float t[32][33];
  int c = threadIdx.x & 31, r = threadIdx.x >> 5;
  #pragma unroll
  for (int i = 0; i < 4; ++i)
    t[r + i*8][c] = src[(size_t)(k0 + r + i*8) * N + n0 + c];
  __syncthreads();
  float* dst = wT + doff;
  #pragma unroll
  for (int i = 0; i < 4; ++i)
    dst[(size_t)(n0 + r + i*8) * K + k0 + c] = t[c][r + i*8];
}

// ---------------- column means (on original layout) ----------------
__global__ void colmean_part_kernel(const float* __restrict__ X, float* __restrict__ part) {
  int bm = blockIdx.x * 256 + threadIdx.x;
  int b = bm >> 9, m = bm & (MM - 1);
  int l0 = blockIdx.y * 128;
  const float* p = X + (size_t)b * LL * MM + (size_t)l0 * MM + m;
  float s = 0.f;
  #pragma unroll 8
  for (int l = 0; l < 128; ++l) s += p[(size_t)l * MM];
  part[(size_t)blockIdx.y * NNODE + bm] = s;
}

__global__ void colmean_finish_kernel(const float* __restrict__ part, float* __restrict__ mu) {
  int bm = blockIdx.x * 256 + threadIdx.x;
  float s = 0.f;
  #pragma unroll
  for (int j = 0; j < 8; ++j) s += part[(size_t)j * NNODE + bm];
  mu[bm] = s * (1.f / 1024.f);
}

// ---------------- MFMA gram: G_z[b] = Xt[b](:,zhalf) @ Xt[b](:,zhalf)^T ----------------
// hi/lo bf16 split, exact to ~2^-17 rel. grid (36 pairs, BB, 2).
__global__ __launch_bounds__(256) void mfma_gram_kernel(const float* __restrict__ XT,
                                                        float* __restrict__ G0,
                                                        float* __restrict__ G1) {
  __shared__ short Ah[4][64][8], Al[4][64][8], Bh[4][64][8], Bl[4][64][8];
  int b = blockIdx.y, z = blockIdx.z;
  int pi = blockIdx.x;
  int ti = 0, rem = pi;
  while (rem >= 8 - ti) { rem -= 8 - ti; ++ti; }
  int tj = ti + rem;
  int m0 = ti * 64, n0 = tj * 64;
  int tid = threadIdx.x;
  int wid = tid >> 6, lane = tid & 63;
  int wr = wid >> 1, wc = wid & 1;
  int srow = tid & 63, skb = tid >> 6;
  const float* Xb = XT + (size_t)b * MM * LL;
  f32x4 acc00 = {0,0,0,0}, acc01 = {0,0,0,0}, acc10 = {0,0,0,0}, acc11 = {0,0,0,0};
  int fr = lane & 15, fkb = lane >> 4;
  for (int k0 = z * 512; k0 < z * 512 + 512; k0 += 32) {
    split8_store(Xb + (size_t)(m0 + srow) * LL + k0 + skb * 8,
                 &Ah[skb][srow][0], &Al[skb][srow][0]);
    split8_store(Xb + (size_t)(n0 + srow) * LL + k0 + skb * 8,
                 &Bh[skb][srow][0], &Bl[skb][srow][0]);
    __syncthreads();
    bf16x8 a0h = *(const bf16x8*)&Ah[fkb][wr*32 + fr][0];
    bf16x8 a1h = *(const bf16x8*)&Ah[fkb][wr*32 + 16 + fr][0];
    bf16x8 a0l = *(const bf16x8*)&Al[fkb][wr*32 + fr][0];
    bf16x8 a1l = *(const bf16x8*)&Al[fkb][wr*32 + 16 + fr][0];
    bf16x8 b0h = *(const bf16x8*)&Bh[fkb][wc*32 + fr][0];
    bf16x8 b1h = *(const bf16x8*)&Bh[fkb][wc*32 + 16 + fr][0];
    bf16x8 b0l = *(const bf16x8*)&Bl[fkb][wc*32 + fr][0];
    bf16x8 b1l = *(const bf16x8*)&Bl[fkb][wc*32 + 16 + fr][0];
    acc00 = MFMA(a0h, b0h, acc00); acc00 = MFMA(a0h, b0l, acc00); acc00 = MFMA(a0l, b0h, acc00);
    acc01 = MFMA(a0h, b1h, acc01); acc01 = MFMA(a0h, b1l, acc01); acc01 = MFMA(a0l, b1h, acc01);
    acc10 = MFMA(a1h, b0h, acc10); acc10 = MFMA(a1h, b0l, acc10); acc10 = MFMA(a1l, b0h, acc10);
    acc11 = MFMA(a1h, b1h, acc11); acc11 = MFMA(a1h, b1l, acc11); acc11 = MFMA(a1l, b1h, acc11);
    __syncthreads();
  }
  float* G = (z ? G1 : G0) + (size_t)b * MM * MM;
  int mirror = (ti != tj);
  #pragma unroll
  for (int i = 0; i < 2; ++i) {
    #pragma unroll
    for (int j = 0; j < 2; ++j) {
      const f32x4& a = (i == 0) ? (j == 0 ? acc00 : acc01) : (j == 0 ? acc10 : acc11);
      #pragma unroll
      for (int r = 0; r < 4; ++r) {
        int row = m0 + wr*32 + i*16 + (lane >> 4)*4 + r;
        int col = n0 + wc*32 + j*16 + (lane & 15);
        float v = a[r];
        G[(size_t)row * MM + col] = v;
        if (mirror) G[(size_t)col * MM + row] = v;
      }
    }
  }
}

// ---------------- MFMA GEMM: C[M,N] = A[M,K] @ Bt[N,K]^T (+bias)(+resid)(relu) --------
__global__ __launch_bounds__(256) void mfma_gemm_kernel(
    const float* __restrict__ A, const float* __restrict__ Bt, float* __restrict__ C,
    int N, int Kd, const float* __restrict__ bias,
    const float* __restrict__ resid, int relu) {
  __shared__ short Ah[4][64][8], Al[4][64][8], Bh[4][64][8], Bl[4][64][8];
  int tid = threadIdx.x;
  int m0 = blockIdx.y * 64, n0 = blockIdx.x * 64;
  int wid = tid >> 6, lane = tid & 63;
  int wr = wid >> 1, wc = wid & 1;
  int srow = tid & 63, skb = tid >> 6;
  f32x4 acc00 = {0,0,0,0}, acc01 = {0,0,0,0}, acc10 = {0,0,0,0}, acc11 = {0,0,0,0};
  int fr = lane & 15, fkb = lane >> 4;
  for (int k0 = 0; k0 < Kd; k0 += 32) {
    split8_store(A  + (size_t)(m0 + srow) * Kd + k0 + skb * 8,
                 &Ah[skb][srow][0], &Al[skb][srow][0]);
    split8_store(Bt + (size_t)(n0 + srow) * Kd + k0 + skb * 8,
                 &Bh[skb][srow][0], &Bl[skb][srow][0]);
    __syncthreads();
    bf16x8 a0h = *(const bf16x8*)&Ah[fkb][wr*32 + fr][0];
    bf16x8 a1h = *(const bf16x8*)&Ah[fkb][wr*32 + 16 + fr][0];
    bf16x8 a0l = *(const bf16x8*)&Al[fkb][wr*32 + fr][0];
    bf16x8 a1l = *(const bf16x8*)&Al[fkb][wr*32 + 16 + fr][0];
    bf16x8 b0h = *(const bf16x8*)&Bh[fkb][wc*32 + fr][0];
    bf16x8 b1h = *(const bf16x8*)&Bh[fkb][wc*32 + 16 + fr][0];
    bf16x8 b0l = *(const bf16x8*)&Bl[fkb][wc*32 + fr][0];
    bf16x8 b1l = *(const bf16x8*)&Bl[fkb][wc*32 + 16 + fr][0];
    acc00 = MFMA(a0h, b0h, acc00); acc00 = MFMA(a0h, b0l, acc00); acc00 = MFMA(a0l, b0h, acc00);
    acc01 = MFMA(a0h, b1h, acc01); acc01 = MFMA(a0h, b1l, acc01); acc01 = MFMA(a0l, b1h, acc01);
    acc10 = MFMA(a1h, b0h, acc10); acc10 = MFMA(a1h, b0l, acc10); acc10 = MFMA(a1l, b0h, acc10);
    acc11 = MFMA(a1h, b1h, acc11); acc11 = MFMA(a1h, b1l, acc11); acc11 = MFMA(a1l, b1h, acc11);
    __syncthreads();
  }
  #pragma unroll
  for (int i = 0; i < 2; ++i) {
    #pragma unroll
    for (int j = 0; j < 2; ++j) {
      const f32x4& a = (i == 0) ? (j == 0 ? acc00 : acc01) : (j == 0 ? acc10 : acc11);
      #pragma unroll
      for (int r = 0; r < 4; ++r) {
        int row = m0 + wr*32 + i*16 + (lane >> 4)*4 + r;
        int col = n0 + wc*32 + j*16 + (lane & 15);
        float v = a[r];
        if (bias)  v += bias[col];
        if (resid) v += resid[(size_t)row * N + col];
        if (relu)  v = fmaxf(v, 0.f);
        C[(size_t)row * N + col] = v;
      }
    }
  }
}

// ---------------- rstd[b,m] = 1/std (std==0 -> 1) ----------------
__global__ void rstd_kernel(const float* __restrict__ G0, const float* __restrict__ G1,
                            const float* __restrict__ mu, float* __restrict__ rstd) {
  int bm = blockIdx.x * 256 + threadIdx.x;
  int b = bm >> 9, m = bm & (MM - 1);
  size_t di = (size_t)b * MM * MM + (size_t)m * MM + m;
  float g = G0[di] + G1[di];
  float mm = mu[bm];
  float cov = (g - 1024.f * mm * mm) * (1.f / 1023.f);
  float sd = sqrtf(fmaxf(cov, 0.f));
  rstd[bm] = (sd == 0.f) ? 1.f : (1.f / sd);
}

// ---------------- neighbors: ascending stable argsort positions 1..16 ----------------
__global__ void select_kernel(const float* __restrict__ G0, const float* __restrict__ G1,
                              const float* __restrict__ mu,
                              const float* __restrict__ rstd, int* __restrict__ nb) {
  int w = threadIdx.x >> 6, lane = threadIdx.x & 63;
  int bm = blockIdx.x * 4 + w;
  int b = bm >> 9, m = bm & (MM - 1);
  size_t rowoff = (size_t)b * MM * MM + (size_t)m * MM;
  const float* Gr0 = G0 + rowoff;
  const float* Gr1 = G1 + rowoff;
  const float* mub = mu + b * MM;
  const float* rsb = rstd + b * MM;
  float mm = mub[m], rm = rsb[m];
  float vals[8];
  int excl = 0;
  #pragma unroll
  for (int j = 0; j < 8; ++j) {
    int n = lane + j * 64;
    float cov = ((Gr0[n] + Gr1[n]) - 1024.f * mm * mub[n]) * (1.f / 1023.f);
    vals[j] = cov * rm * rsb[n];
  }
  int* out = nb + (size_t)bm * KK;
  for (int it = 0; it < KK + 1; ++it) {
    float bv = 1e30f; int bi = 1 << 30;
    #pragma unroll
    for (int j = 0; j < 8; ++j) {
      if (!((excl >> j) & 1)) {
        int n = lane + j * 64;
        if (vals[j] < bv) { bv = vals[j]; bi = n; }
      }
    }
    for (int off = 32; off; off >>= 1) {
      float v2 = __shfl_down(bv, off);
      int   i2 = __shfl_down(bi, off);
      if (v2 < bv || (v2 == bv && i2 < bi)) { bv = v2; bi = i2; }
    }
    bi = __shfl(bi, 0);
    if ((bi & 63) == lane) excl |= 1 << (bi >> 6);
    if (it > 0 && lane == 0) out[it - 1] = bi;
  }
}

// ---------------- degree counts ----------------
__global__ void count_kernel(const int* __restrict__ nb, int* __restrict__ cnt) {
  int e = blockIdx.x * 256 + threadIdx.x;
  int b = e >> 13, i = e & 8191;
  int dst = b * MM + nb[(size_t)b * 8192 + i];
  atomicAdd(&cnt[dst], 1);
}

// ---------------- scan + cursor + dinv ----------------
__global__ void scan_kernel(const int* __restrict__ cnt, int* __restrict__ offs,
                            int* __restrict__ curs, float* __restrict__ dinv) {
  __shared__ int part[256];
  int tid = threadIdx.x;
  int base = tid * 32;
  int local[32];
  int s = 0;
  #pragma unroll
  for (int i = 0; i < 32; ++i) { local[i] = cnt[base + i]; s += local[i]; }
  part[tid] = s;
  __syncthreads();
  for (int off = 1; off < 256; off <<= 1) {
    int v = (tid >= off) ? part[tid - off] : 0;
    __syncthreads();
    part[tid] += v;
    __syncthreads();
  }
  int run = part[tid] - s;
  #pragma unroll
  for (int i = 0; i < 32; ++i) {
    int n = base + i;
    offs[n] = run; curs[n] = run;
    run += local[i];
    dinv[n] = rsqrtf((float)(local[i] + 1));
  }
  if (tid == 255) offs[NNODE] = run;
}

// ---------------- scatter reverse edge lists ----------------
__global__ void scatter_kernel(const int* __restrict__ nb, int* __restrict__ curs,
                               int* __restrict__ lists) {
  int e = blockIdx.x * 256 + threadIdx.x;
  int b = e >> 13, i = e & 8191;
  int dst = b * MM + nb[(size_t)b * 8192 + i];
  int src = b * MM + (i & (MM - 1));
  int pos = atomicAdd(&curs[dst], 1);
  lists[pos] = src;
}

// ---------------- GCN aggregation ----------------
__global__ void agg_kernel(const float* __restrict__ xw, const float* __restrict__ dinv,
                           const int* __restrict__ offs, const int* __restrict__ lists,
                           const float* __restrict__ bias, float* __restrict__ out) {
  int n = blockIdx.x * 2 + (threadIdx.x >> 7);
  int c = threadIdx.x & 127;
  float dn = dinv[n];
  float s = dn * xw[(size_t)n * DD + c];
  int e0 = offs[n], e1 = offs[n + 1];
  for (int e = e0; e < e1; ++e) {
    int src = lists[e];
    s += dinv[src] * xw[(size_t)src * DD + c];
  }
  float v = dn * s + bias[c];
  out[(size_t)n * DD + c] = fmaxf(v, 0.f);
}

// ---------------- fused attention (online softmax), dh=16, full 512 keys ----------------
#define KS(arr, r, j) arr[((r) << 4) + (((r) >> 6) << 3) + (j)]
__global__ __launch_bounds__(256) void attn_kernel(
    const float* __restrict__ qh, const float* __restrict__ kh,
    const float* __restrict__ vh, float* __restrict__ out) {
  __shared__ float ks[256 * 16 + 24];
  __shared__ float vs[256 * 16 + 24];
  int bx = blockIdx.x;
  int qc = bx & 7;
  int h  = (bx >> 3) & 7;
  int b  = bx >> 6;
  int tid = threadIdx.x;
  int r = tid >> 2;
  int p = tid & 3;
  int qrow = b * MM + qc * 64 + r;
  float qv[16];
  const float* qp = qh + (size_t)qrow * DD + h * DHH;
  #pragma unroll
  for (int j = 0; j < 16; ++j) qv[j] = qp[j];
  float mval = -1e30f, l = 0.f;
  float o[16];
  #pragma unroll
  for (int j = 0; j < 16; ++j) o[j] = 0.f;
  for (int ch = 0; ch < 2; ++ch) {
    __syncthreads();
    for (int idx = tid; idx < 256 * 4; idx += 256) {
      int row = idx >> 2, seg = idx & 3;
      int krow = b * MM + ch * 256 + row;
      *(float4*)&KS(ks, row, seg * 4) = *(const float4*)&kh[(size_t)krow * DD + h * DHH + seg * 4];
      *(float4*)&KS(vs, row, seg * 4) = *(const float4*)&vh[(size_t)krow * DD + h * DHH + seg * 4];
    }
    __syncthreads();
    for (int kk = p * 64; kk < p * 64 + 64; ++kk) {
      float s = 0.f;
      #pragma unroll
      for (int j = 0; j < 16; ++j) s += qv[j] * KS(ks, kk, j);
      s *= 0.25f;
      float nm = fmaxf(mval, s);
      float scale = __expf(mval - nm);
      float pw = __expf(s - nm);
      l = l * scale + pw;
      #pragma unroll
      for (int j = 0; j < 16; ++j) o[j] = o[j] * scale + pw * KS(vs, kk, j);
      mval = nm;
    }
  }
  #pragma unroll
  for (int off = 1; off <= 2; off <<= 1) {
    float m2 = __shfl_xor(mval, off);
    float l2 = __shfl_xor(l, off);
    float nm = fmaxf(mval, m2);
    float s1 = __expf(mval - nm), s2 = __expf(m2 - nm);
    l = l * s1 + l2 * s2;
    #pragma unroll
    for (int j = 0; j < 16; ++j) {
      float o2 = __shfl_xor(o[j], off);
      o[j] = o[j] * s1 + o2 * s2;
    }
    mval = nm;
  }
  if (p == 0) {
    float invl = 1.f / l;
    float* op = out + (size_t)qrow * DD + h * DHH;
    #pragma unroll
    for (int j = 0; j < 16; ++j) op[j] = o[j] * invl;
  }
}

// ---------------- layernorm over D=128 ----------------
__global__ void ln_kernel(const float* __restrict__ x, const float* __restrict__ g,
                          const float* __restrict__ bb, float* __restrict__ out) {
  int row = blockIdx.x * 4 + (threadIdx.x >> 6);
  int lane = threadIdx.x & 63;
  float2 xv = *(const float2*)&x[(size_t)row * DD + lane * 2];
  float s = xv.x + xv.y;
  #pragma unroll
  for (int off = 1; off < 64; off <<= 1) s += __shfl_xor(s, off);
  float mu = s * (1.f / 128.f);
  float d0 = xv.x - mu, d1 = xv.y - mu;
  float sq = d0 * d0 + d1 * d1;
  #pragma unroll
  for (int off = 1; off < 64; off <<= 1) sq += __shfl_xor(sq, off);
  float rs = rsqrtf(sq * (1.f / 128.f) + 1e-5f);
  float2 gg = *(const float2*)&g[lane * 2];
  float2 bv = *(const float2*)&bb[lane * 2];
  float2 y;
  y.x = d0 * rs * gg.x + bv.x;
  y.y = d1 * rs * gg.y + bv.y;
  *(float2*)&out[(size_t)row * DD + lane * 2] = y;
}

extern "C" void kernel_launch(void* const* d_in, const int* in_sizes, int n_in,
                              void* d_out, int out_size, void* d_ws, size_t ws_size,
                              hipStream_t stream) {
  (void)in_sizes; (void)n_in; (void)out_size; (void)ws_size;
  const float* enc  = (const float*)d_in[0];
  const float* xenc = (const float*)d_in[1];
  const float* gw1  = (const float*)d_in[2];
  const float* gb1  = (const float*)d_in[3];
  const float* gw2  = (const float*)d_in[4];
  const float* gb2  = (const float*)d_in[5];
  const float* Wq   = (const float*)d_in[6];
  const float* Wk   = (const float*)d_in[7];
  const float* Wv   = (const float*)d_in[8];
  const float* Wo   = (const float*)d_in[9];
  const float* ln1g = (const float*)d_in[10];
  const float* ln1b = (const float*)d_in[11];
  const float* W1   = (const float*)d_in[12];
  const float* b1   = (const float*)d_in[13];
  const float* W2   = (const float*)d_in[14];
  const float* b2   = (const float*)d_in[15];
  const float* ln2g = (const float*)d_in[16];
  const float* ln2b = (const float*)d_in[17];
  float* outp = (float*)d_out;

  char* w = (char*)d_ws;
  auto alloc = [&](size_t bytes) -> char* {
    char* p = w;
    w += (bytes + 255) & ~(size_t)255;
    return p;
  };
  float* mu    = (float*)alloc((size_t)NNODE * 4);
  float* rstd  = (float*)alloc((size_t)NNODE * 4);
  float* dinv  = (float*)alloc((size_t)NNODE * 4);
  float* mpart = (float*)alloc((size_t)8 * NNODE * 4);
  int*   nb    = (int*)  alloc((size_t)NEDGE * 4);
  int*   cnt   = (int*)  alloc((size_t)NNODE * 4);
  int*   offs  = (int*)  alloc((size_t)(NNODE + 1) * 4);
  int*   curs  = (int*)  alloc((size_t)NNODE * 4);
  int*   lists = (int*)  alloc((size_t)NEDGE * 4);
  float* gram  = (float*)alloc((size_t)BB * MM * MM * 4);        // 16 MB, reused
  float* kvb   = (float*)alloc((size_t)NNODE * DD * 4);
  float* bufx  = (float*)alloc((size_t)NNODE * DD * 4);
  float* bufxl = (float*)alloc((size_t)NNODE * DD * 4);
  float* bufh  = (float*)alloc((size_t)NNODE * DD * 4);
  float* bufh1 = (float*)alloc((size_t)NNODE * DD * 4);
  float* xt    = (float*)alloc((size_t)BB * MM * LL * 4);        // 32 MB transposed x
  float* wT    = (float*)alloc((size_t)425984 * 4);              // transposed weights
  float* SA = gram;
  float* SB = gram + (size_t)1048576;
  float* SC = gram + (size_t)2097152;
  float* SD = gram + (size_t)3145728;
  // Second gram partial aliases kvb..bufh (16 MB) — dead until after select_kernel.
  float* gram2 = kvb;

  const float* gw1T = wT;
  const float* gw2T = wT + 16384;
  auto WqT = [&](int l) { return wT + (size_t)(2 + l) * 16384; };
  auto WkT = [&](int l) { return wT + (size_t)(4 + l) * 16384; };
  auto WvT = [&](int l) { return wT + (size_t)(6 + l) * 16384; };
  auto WoT = [&](int l) { return wT + (size_t)(8 + l) * 16384; };
  auto W1T = [&](int l) { return wT + 163840 + (size_t)l * 65536; };
  auto W2T = [&](int l) { return wT + 294912 + (size_t)l * 65536; };

  auto gemm = [&](const float* A, const float* Bt, float* C, int Mr, int N, int Kd,
                  const float* bias, const float* resid, int relu) {
    dim3 g(N / 64, Mr / 64);
    mfma_gemm_kernel<<<g, 256, 0, stream>>>(A, Bt, C, N, Kd, bias, resid, relu);
  };

  // ---- transposes ----
  transpose_x_kernel<<<dim3(16, 32, 16), 256, 0, stream>>>(xenc, xt);
  transpose_w_kernel<<<dim3(16, 16, 14), 256, 0, stream>>>(gw1, gw2, Wq, Wk, Wv, Wo, W1, W2, wT);

  // ---- graph build ----
  colmean_part_kernel<<<dim3(32, 8), 256, 0, stream>>>(xenc, mpart);
  colmean_finish_kernel<<<NNODE / 256, 256, 0, stream>>>(mpart, mu);
  mfma_gram_kernel<<<dim3(36, BB, 2), 256, 0, stream>>>(xt, gram, gram2);
  rstd_kernel<<<NNODE / 256, 256, 0, stream>>>(gram, gram2, mu, rstd);
  select_kernel<<<NNODE / 4, 256, 0, stream>>>(gram, gram2, mu, rstd, nb);
  hipMemsetAsync(cnt, 0, (size_t)NNODE * 4, stream);
  count_kernel<<<NEDGE / 256, 256, 0, stream>>>(nb, cnt);
  scan_kernel<<<1, 256, 0, stream>>>(cnt, offs, curs, dinv);
  scatter_kernel<<<NEDGE / 256, 256, 0, stream>>>(nb, curs, lists);

  // ---- 2-layer GCN ----
  gemm(enc, gw1T, SA, NNODE, DD, DD, nullptr, nullptr, 0);
  agg_kernel<<<NNODE / 2, 256, 0, stream>>>(SA, dinv, offs, lists, gb1, SB);
  gemm(SB, gw2T, SC, NNODE, DD, DD, nullptr, nullptr, 0);
  agg_kernel<<<NNODE / 2, 256, 0, stream>>>(SC, dinv, offs, lists, gb2, kvb);

  // ---- transformer encoder layers ----
  for (int l = 0; l < 2; ++l) {
    const float* hq = (l == 0) ? enc : bufh1;
    gemm(hq,  WqT(l), SA, NNODE, DD, DD, nullptr, nullptr, 0);
    gemm(kvb, WkT(l), SB, NNODE, DD, DD, nullptr, nullptr, 0);
    gemm(kvb, WvT(l), SC, NNODE, DD, DD, nullptr, nullptr, 0);
    attn_kernel<<<BB * HH * 8, 256, 0, stream>>>(SA, SB, SC, SD);
    gemm(SD, WoT(l), bufx, NNODE, DD, DD, nullptr, hq, 0);
    ln_kernel<<<NNODE / 4, 256, 0, stream>>>(bufx, ln1g + l * DD, ln1b + l * DD, bufxl);
    gemm(bufxl, W1T(l), gram, NNODE, NDFF, DD, b1 + l * NDFF, nullptr, 1);
    gemm(gram, W2T(l), bufh, NNODE, DD, NDFF, b2 + l * DD, bufxl, 0);
    ln_kernel<<<NNODE / 4, 256, 0, stream>>>(bufh, ln2g + l * DD, ln2b + l * DD,
                                             (l == 1) ? outp : bufh1);
  }
}